// Round 10
// baseline (3515.235 us; speedup 1.0000x reference)
//
#include <hip/hip_runtime.h>

typedef _Float16 half8 __attribute__((ext_vector_type(8)));
typedef float floatx4 __attribute__((ext_vector_type(4)));
typedef unsigned long long u64;

#define T_STEPS 512
#define IN_DIM 256
#define HID 512
#define RING 8

__device__ inline float sig_f(float x) { return 1.f / (1.f + __expf(-x)); }
__device__ inline float tanh_f(float x) {
  float t = __expf(-2.f * fabsf(x));
  return copysignf((1.f - t) / (1.f + t), x);
}

// ---- LLC-coherent (agent-scope) scalar accessors — proven in R3/R9 ----
__device__ inline void cstore_pair(_Float16* p, float a, float b) {
  union { unsigned u; _Float16 h[2]; } pk;
  pk.h[0] = (_Float16)a; pk.h[1] = (_Float16)b;
  __hip_atomic_store((unsigned*)p, pk.u, __ATOMIC_RELAXED, __HIP_MEMORY_SCOPE_AGENT);
}
__device__ inline unsigned poll_llc(const unsigned* p) {
  return __hip_atomic_load(p, __ATOMIC_RELAXED, __HIP_MEMORY_SCOPE_AGENT);
}
__device__ inline u64 cload64(const _Float16* p) {
  return __hip_atomic_load((const u64*)p, __ATOMIC_RELAXED, __HIP_MEMORY_SCOPE_AGENT);
}
__device__ inline half8 cload_h8(const _Float16* p) {
  union { u64 u[2]; half8 v; } r;
  r.u[0] = cload64(p);
  r.u[1] = cload64(p + 4);
  return r.v;
}

// ---- batched LLC loads: 16x16B from one base (offsets 0..960, 64B stride). ----
#define LD16_OPS(W)                                           \
      "global_load_dwordx4 %0, %16, off sc0 sc1\n\t"          \
      "global_load_dwordx4 %1, %16, off offset:64 sc0 sc1\n\t"   \
      "global_load_dwordx4 %2, %16, off offset:128 sc0 sc1\n\t"  \
      "global_load_dwordx4 %3, %16, off offset:192 sc0 sc1\n\t"  \
      "global_load_dwordx4 %4, %16, off offset:256 sc0 sc1\n\t"  \
      "global_load_dwordx4 %5, %16, off offset:320 sc0 sc1\n\t"  \
      "global_load_dwordx4 %6, %16, off offset:384 sc0 sc1\n\t"  \
      "global_load_dwordx4 %7, %16, off offset:448 sc0 sc1\n\t"  \
      "global_load_dwordx4 %8, %16, off offset:512 sc0 sc1\n\t"  \
      "global_load_dwordx4 %9, %16, off offset:576 sc0 sc1\n\t"  \
      "global_load_dwordx4 %10, %16, off offset:640 sc0 sc1\n\t" \
      "global_load_dwordx4 %11, %16, off offset:704 sc0 sc1\n\t" \
      "global_load_dwordx4 %12, %16, off offset:768 sc0 sc1\n\t" \
      "global_load_dwordx4 %13, %16, off offset:832 sc0 sc1\n\t" \
      "global_load_dwordx4 %14, %16, off offset:896 sc0 sc1\n\t" \
      "global_load_dwordx4 %15, %16, off offset:960 sc0 sc1" W

#define LD16_OUTS                                                          \
      : "=&v"(t0), "=&v"(t1), "=&v"(t2), "=&v"(t3), "=&v"(t4), "=&v"(t5),  \
        "=&v"(t6), "=&v"(t7), "=&v"(t8), "=&v"(t9), "=&v"(t10),            \
        "=&v"(t11), "=&v"(t12), "=&v"(t13), "=&v"(t14), "=&v"(t15)         \
      : "v"(base)                                                          \
      : "memory"

#define LD16_STORE                                                          \
  r[0] = __builtin_bit_cast(half8, t0);  r[1] = __builtin_bit_cast(half8, t1);  \
  r[2] = __builtin_bit_cast(half8, t2);  r[3] = __builtin_bit_cast(half8, t3);  \
  r[4] = __builtin_bit_cast(half8, t4);  r[5] = __builtin_bit_cast(half8, t5);  \
  r[6] = __builtin_bit_cast(half8, t6);  r[7] = __builtin_bit_cast(half8, t7);  \
  r[8] = __builtin_bit_cast(half8, t8);  r[9] = __builtin_bit_cast(half8, t9);  \
  r[10] = __builtin_bit_cast(half8, t10); r[11] = __builtin_bit_cast(half8, t11); \
  r[12] = __builtin_bit_cast(half8, t12); r[13] = __builtin_bit_cast(half8, t13); \
  r[14] = __builtin_bit_cast(half8, t14); r[15] = __builtin_bit_cast(half8, t15)

// Issue 16 loads, NO waitcnt (pair with a later ld16_wait + pin16).
__device__ inline void ld16_issue(const _Float16* base, half8 (&r)[16]) {
  floatx4 t0, t1, t2, t3, t4, t5, t6, t7, t8, t9, t10, t11, t12, t13, t14, t15;
  asm volatile(LD16_OPS("") LD16_OUTS);
  LD16_STORE;
}
// Issue 16 loads + s_waitcnt vmcnt(0) — drains ALL outstanding vmem (incl. a
// preceding ld16_issue), so one RTT covers both batches.
__device__ inline void ld16_wait(const _Float16* base, half8 (&r)[16]) {
  floatx4 t0, t1, t2, t3, t4, t5, t6, t7, t8, t9, t10, t11, t12, t13, t14, t15;
  asm volatile(LD16_OPS("\n\ts_waitcnt vmcnt(0)") LD16_OUTS);
  LD16_STORE;
}
// Ordering fence: marks r[] as rewritten so no consumer of a prior ld16_issue
// can be scheduled before this point (place right after ld16_wait).
__device__ inline void pin16(half8 (&r)[16]) {
  asm volatile(""
               : "+v"(r[0]), "+v"(r[1]), "+v"(r[2]), "+v"(r[3]), "+v"(r[4]),
                 "+v"(r[5]), "+v"(r[6]), "+v"(r[7]), "+v"(r[8]), "+v"(r[9]),
                 "+v"(r[10]), "+v"(r[11]), "+v"(r[12]), "+v"(r[13]),
                 "+v"(r[14]), "+v"(r[15]));
}

// Wave-parallel wait on 64 flags (call from one full wave; others at barrier).
__device__ inline void waitf(const unsigned* fg, unsigned tg) {
  if (tg == 0) return;
  const unsigned* p = fg + (threadIdx.x & 63) * 32;
  int it = 0;
  while (!__all((int)(poll_llc(p) >= tg))) {
    if (++it > 4) __builtin_amdgcn_s_sleep(1);
  }
}

__device__ inline floatx4 mfma16(half8 a, half8 b, floatx4 c) {
  return __builtin_amdgcn_mfma_f32_16x16x32_f16(a, b, c, 0, 0, 0);
}

__global__ void init_kernel(const float* __restrict__ x, const float* __restrict__ hc,
                            _Float16* __restrict__ x16, _Float16* __restrict__ h0b,
                            _Float16* __restrict__ h1b, unsigned* __restrict__ flagbase) {
  size_t i = (size_t)blockIdx.x * blockDim.x + threadIdx.x;
  size_t stride = (size_t)gridDim.x * blockDim.x;
  const size_t n = (size_t)T_STEPS * 64 * IN_DIM;
  for (size_t idx = i; idx < n; idx += stride) x16[idx] = (_Float16)x[idx];
  if (i < 16384) {
    // h0[-1] -> ring slot 7; h1[-1] -> parity 1 (LLC-coherent stores).
    cstore_pair(h0b + (size_t)(RING - 1) * 32768 + 2 * i, hc[2 * i], hc[2 * i + 1]);
    cstore_pair(h1b + 32768 + 2 * i, hc[32768 + 2 * i], hc[32768 + 2 * i + 1]);
  }
  if (i < 4096) {  // zero both flag arrays (2 x 8192 B contiguous)
    __hip_atomic_store(flagbase + i, 0u, __ATOMIC_RELAXED, __HIP_MEMORY_SCOPE_AGENT);
  }
}

// R9 skeleton: blocks 0..63 = L0 (8 h-cols each), 64..127 = L1. LLC-only
// coherence. Changes vs R9: (1) L1's two waits polled in parallel by separate
// waves; (2) each GEMM's h loads are one 16-load batch; L1's two batches share
// a single vmcnt(0) (issue + wait + pin), ~1 RTT for 32 loads.
__global__ __launch_bounds__(256) void lstm_kernel(
    const _Float16* __restrict__ x16, _Float16* __restrict__ h0b, _Float16* __restrict__ h1b,
    unsigned* __restrict__ flags0, unsigned* __restrict__ flags1,
    const float* __restrict__ W_ih0, const float* __restrict__ W_hh0,
    const float* __restrict__ b_ih0, const float* __restrict__ b_hh0,
    const float* __restrict__ W_ih1, const float* __restrict__ W_hh1,
    const float* __restrict__ b_ih1, const float* __restrict__ b_hh1,
    const float* __restrict__ W_out, const float* __restrict__ b_out,
    const float* __restrict__ hc, float* __restrict__ out) {
  __shared__ __align__(16) _Float16 wlds[32 * 1032];
  __shared__ float cbuf[64 * 36];
  __shared__ float cstate[512];
  __shared__ float blds[32];

  const int bq = blockIdx.x;
  const bool isL0 = bq < 64;
  const int q = isL0 ? bq : bq - 64;
  const int col0 = q * 8;
  const int Ka = isL0 ? IN_DIM : HID;
  const int K = Ka + HID;
  const int WP = K + 8;
  const float* Wa = isL0 ? W_ih0 : W_ih1;
  const float* Wb = isL0 ? W_hh0 : W_hh1;
  const float* bia = isL0 ? b_ih0 : b_ih1;
  const float* bib = isL0 ? b_hh0 : b_hh1;
  unsigned* myflag = (isL0 ? flags0 : flags1) + q * 32;

  for (int idx = threadIdx.x; idx < 32 * K; idx += 256) {
    int r = idx / K;
    int k = idx - r * K;
    int g = r >> 3, j = r & 7;
    int grow = g * HID + col0 + j;  // PyTorch gate order i,f,g,o
    float w = (k < Ka) ? Wa[(size_t)grow * Ka + k] : Wb[(size_t)grow * HID + (k - Ka)];
    wlds[r * WP + k] = (_Float16)w;
  }
  if (threadIdx.x < 32) {
    int g = threadIdx.x >> 3, j = threadIdx.x & 7;
    int grow = g * HID + col0 + j;
    blds[threadIdx.x] = bia[grow] + bib[grow];
  }
  {
    int layer = isL0 ? 0 : 1;
    for (int idx = threadIdx.x; idx < 512; idx += 256) {
      int m = idx >> 3, j = idx & 7;
      cstate[idx] = hc[(size_t)(2 + layer) * 32768 + m * HID + col0 + j];
    }
  }
  __syncthreads();

  const int lane = threadIdx.x & 63;
  const int wv = threadIdx.x >> 6;   // 0..3
  const int lrow = lane & 15;
  const int kq = (lane >> 4) * 8;
  const int m0 = wv * 16;
  const _Float16* wrow0 = wlds + lrow * WP;
  const _Float16* wrow1 = wlds + (16 + lrow) * WP;

  // Recurrent-half B fragments (compiler keeps/remats from LDS as it prefers).
  half8 breg0[16], breg1[16];
#pragma unroll
  for (int c = 0; c < 16; ++c) {
    breg0[c] = *(const half8*)(wrow0 + Ka + c * 32 + kq);
    breg1[c] = *(const half8*)(wrow1 + Ka + c * 32 + kq);
  }

  const int gm = threadIdx.x >> 2;
  const int gj = (threadIdx.x & 3) * 2;

  for (int t = 0; t < T_STEPS; ++t) {
    floatx4 acc0 = {0.f, 0.f, 0.f, 0.f};
    floatx4 acc1 = {0.f, 0.f, 0.f, 0.f};
    _Float16* dst;

    if (isL0) {
      // X phase (no cross-block dep): compute before the wait.
      const _Float16* a0p = x16 + (size_t)t * (64 * IN_DIM) + (m0 + lrow) * IN_DIM + kq;
#pragma unroll
      for (int c = 0; c < 8; ++c) {
        half8 a = *(const half8*)(a0p + c * 32);
        half8 b0v = *(const half8*)(wrow0 + c * 32 + kq);
        half8 b1v = *(const half8*)(wrow1 + c * 32 + kq);
        acc0 = mfma16(a, b0v, acc0);
        acc1 = mfma16(a, b1v, acc1);
      }
      // Parallel waits: wave0 -> peers' h0[t-1]; wave1 -> ring slot free.
      if (threadIdx.x < 64) waitf(flags0, (unsigned)t);
      else if (threadIdx.x < 128) waitf(flags1, (t >= RING) ? (unsigned)(t - RING + 1) : 0u);
      __syncthreads();
      asm volatile("" ::: "memory");
      const _Float16* a1p = h0b + (size_t)((t - 1) & (RING - 1)) * 32768 + (m0 + lrow) * HID + kq;
      half8 av[16];
      ld16_wait(a1p, av);
#pragma unroll
      for (int c = 0; c < 16; ++c) {
        acc0 = mfma16(av[c], breg0[c], acc0);
        acc1 = mfma16(av[c], breg1[c], acc1);
      }
      dst = h0b + (size_t)(t & (RING - 1)) * 32768;
    } else {
      // Parallel waits: wave0 -> h0[t] ready; wave1 -> peers' h1[t-1].
      if (threadIdx.x < 64) waitf(flags0, (unsigned)(t + 1));
      else if (threadIdx.x < 128) waitf(flags1, (unsigned)t);
      __syncthreads();
      asm volatile("" ::: "memory");
      const _Float16* a0p = h0b + (size_t)(t & (RING - 1)) * 32768 + (m0 + lrow) * HID + kq;
      const _Float16* a1p = h1b + (size_t)((t - 1) & 1) * 32768 + (m0 + lrow) * HID + kq;
      half8 avI[16], avR[16];
      ld16_issue(a0p, avI);   // in-GEMM batch, no waitcnt
      ld16_wait(a1p, avR);    // rec batch + vmcnt(0) draining BOTH
      pin16(avI);             // order avI consumption after the drain
#pragma unroll
      for (int c = 0; c < 16; ++c) {
        half8 b0v = *(const half8*)(wrow0 + c * 32 + kq);
        half8 b1v = *(const half8*)(wrow1 + c * 32 + kq);
        acc0 = mfma16(avI[c], b0v, acc0);
        acc1 = mfma16(avI[c], b1v, acc1);
      }
#pragma unroll
      for (int c = 0; c < 16; ++c) {
        acc0 = mfma16(avR[c], breg0[c], acc0);
        acc1 = mfma16(avR[c], breg1[c], acc1);
      }
      dst = h1b + (size_t)(t & 1) * 32768;
    }

    // C/D layout: col = lane&15 (gate row), row = (lane>>4)*4 + reg (batch)
    const int mrow = m0 + (lane >> 4) * 4;
#pragma unroll
    for (int r2 = 0; r2 < 4; ++r2) {
      cbuf[(mrow + r2) * 36 + lrow] = acc0[r2];
      cbuf[(mrow + r2) * 36 + 16 + lrow] = acc1[r2];
    }
    __syncthreads();

    float hv[2];
#pragma unroll
    for (int e = 0; e < 2; ++e) {
      int j = gj + e;
      float xi = cbuf[gm * 36 + j] + blds[j];
      float xf = cbuf[gm * 36 + 8 + j] + blds[8 + j];
      float xg = cbuf[gm * 36 + 16 + j] + blds[16 + j];
      float xo = cbuf[gm * 36 + 24 + j] + blds[24 + j];
      float ig = sig_f(xi), fg = sig_f(xf), gg = tanh_f(xg), og = sig_f(xo);
      float c = fg * cstate[gm * 8 + j] + ig * gg;
      cstate[gm * 8 + j] = c;
      hv[e] = og * tanh_f(c);
    }
    cstore_pair(dst + gm * HID + col0 + gj, hv[0], hv[1]);

    // Release: drain stores, join block, one flag store.
    asm volatile("s_waitcnt vmcnt(0)" ::: "memory");
    __syncthreads();
    if (threadIdx.x == 0) {
      __hip_atomic_store(myflag, (unsigned)(t + 1), __ATOMIC_RELAXED, __HIP_MEMORY_SCOPE_AGENT);
    }
    asm volatile("" ::: "memory");
  }

  // Final linear on L0 blocks: out[64,256] = h1[511] @ W_out^T + b_out.
  if (isL0) {
    if (threadIdx.x < 64) waitf(flags1, (unsigned)T_STEPS);
    __syncthreads();
    asm volatile("" ::: "memory");
    const int oc = q * 4 + (threadIdx.x & 3);
    const int m = threadIdx.x >> 2;
    const _Float16* hrow = h1b + 32768 + m * HID;  // h1[511] at parity 1
    const float* wrow = W_out + (size_t)oc * HID;
    float sum = 0.f;
#pragma unroll 4
    for (int h = 0; h < HID; h += 8) {
      half8 hvv = cload_h8(hrow + h);
#pragma unroll
      for (int e = 0; e < 8; ++e) sum += (float)hvv[e] * wrow[h + e];
    }
    out[m * 256 + oc] = sum + b_out[oc];
  }
}

extern "C" void kernel_launch(void* const* d_in, const int* in_sizes, int n_in,
                              void* d_out, int out_size, void* d_ws, size_t ws_size,
                              hipStream_t stream) {
  const float* x     = (const float*)d_in[0];
  const float* hc    = (const float*)d_in[1];
  const float* W_ih0 = (const float*)d_in[2];
  const float* W_hh0 = (const float*)d_in[3];
  const float* b_ih0 = (const float*)d_in[4];
  const float* b_hh0 = (const float*)d_in[5];
  const float* W_ih1 = (const float*)d_in[6];
  const float* W_hh1 = (const float*)d_in[7];
  const float* b_ih1 = (const float*)d_in[8];
  const float* b_hh1 = (const float*)d_in[9];
  const float* W_out = (const float*)d_in[10];
  const float* b_out = (const float*)d_in[11];
  float* out = (float*)d_out;

  char* ws = (char*)d_ws;
  _Float16* x16 = (_Float16*)ws;                              // 16 MB
  _Float16* h0b = (_Float16*)(ws + 16777216);                 // 8 x 64 KB ring
  _Float16* h1b = (_Float16*)(ws + 16777216 + 8 * 65536);     // 2 x 64 KB
  unsigned* flags0 = (unsigned*)(ws + 16777216 + 10 * 65536);           // 64 x 128 B
  unsigned* flags1 = (unsigned*)(ws + 16777216 + 10 * 65536 + 8192);    // 64 x 128 B

  init_kernel<<<2048, 256, 0, stream>>>(x, hc, x16, h0b, h1b, flags0);
  lstm_kernel<<<128, 256, 0, stream>>>(x16, h0b, h1b, flags0, flags1,
                                       W_ih0, W_hh0, b_ih0, b_hh0,
                                       W_ih1, W_hh1, b_ih1, b_hh1,
                                       W_out, b_out, hc, out);
}